// Round 2
// baseline (20302.885 us; speedup 1.0000x reference)
//
#include <hip/hip_runtime.h>
#include <hip/hip_bf16.h>
#include <cstdint>

#define B_ 32
#define L_ 196
#define D_ 512
#define H_ 512
#define E_ 256
#define T_ 128
#define V_ 512

using u16 = unsigned short;

__device__ __forceinline__ float bf2f(u16 u) { return __uint_as_float(((unsigned)u) << 16); }
__device__ __forceinline__ u16 f2bf(float f) {
    unsigned u = __float_as_uint(f);
    return (u16)((u + 0x7FFFu + ((u >> 16) & 1u)) >> 16);
}
__device__ __forceinline__ float sigm(float x) { return 1.f / (1.f + __expf(-x)); }

// ---------------- dtype detect: bf16 vs fp32 inputs ----------------
// bf16 weights (N(0,0.02^2)) all have exponent field in [100,130]; fp32 read as
// u16 pairs has ~half near-uniform halves -> ~36/64 plausible. Threshold 56.
__global__ void detect_kernel(const u16* __restrict__ w, int* __restrict__ flg) {
    if (threadIdx.x == 0) {
        int cnt = 0;
        for (int i = 0; i < 64; ++i) {
            int e = (w[i] >> 7) & 0xFF;
            cnt += (e >= 100 && e <= 130);
        }
        flg[0] = (cnt >= 56) ? 1 : 0;
    }
}

// ---------------- convert all float tensors to internal bf16 ----------------
struct ConvPtrs { const void* p[19]; };

__global__ __launch_bounds__(256) void conv_kernel(ConvPtrs cp, const int* __restrict__ flg,
                                                   u16* __restrict__ dst) {
    constexpr int NT = 19;
    constexpr unsigned off[NT + 1] = {
        0u, 3211264u, 3227648u, 3244032u, 3440640u, 3440896u, 3473664u, 3473792u,
        3473920u, 5046784u, 6095360u, 6097408u, 6099456u, 6230528u, 6688768u,
        6689128u, 6817296u, 6817656u, 7000952u, 7001464u};
    constexpr unsigned realN[NT] = {
        3211264u, 16384u, 16384u, 196608u, 256u, 32768u, 128u, 128u,
        1572864u, 1048576u, 2048u, 2048u, 131072u, 458240u, 358u,
        128164u, 358u, 183296u, 512u};
    unsigned pos = (blockIdx.x * 256u + threadIdx.x) * 4u;
    if (pos >= off[NT]) return;
    int t = 0;
#pragma unroll
    for (int i = 1; i < NT; ++i) t += (pos >= off[i]);
    unsigned local = pos - off[t];
    int bf = flg[0];
    const void* src = cp.p[t];
    u16* d = dst + off[t];
#pragma unroll
    for (int j = 0; j < 4; ++j) {
        unsigned l = local + j;
        u16 v = 0;
        if (l < realN[t]) v = bf ? ((const u16*)src)[l] : f2bf(((const float*)src)[l]);
        d[l] = v;
    }
}

// ---------------- embedding (shifted y) -> hze e-part ----------------
__global__ __launch_bounds__(256) void embed_kernel(const int* __restrict__ y,
                                                    const u16* __restrict__ emb,
                                                    u16* __restrict__ hze) {
    int t = threadIdx.x;
    int row0 = blockIdx.x * 4;
    for (int i = 0; i < 4; ++i) {
        int row = row0 + i;
        int b = row >> 7, tt = row & 127;
        int yin = tt ? y[b * T_ + tt - 1] : 0;
        hze[(size_t)row * 1280 + 1024 + t] = emb[yin * E_ + t];
    }
}

// ---------------- init h,c + first hterm ----------------
__global__ __launch_bounds__(256) void init_kernel(const u16* __restrict__ h0,
                                                   const u16* __restrict__ c0,
                                                   const u16* __restrict__ att_w1,
                                                   float* __restrict__ h_buf,
                                                   float* __restrict__ c_buf,
                                                   float* __restrict__ hterm) {
    int b = blockIdx.x, t = threadIdx.x;
    __shared__ float hs[512];
    for (int i = t; i < 512; i += 256) {
        float hv = bf2f(h0[b * 512 + i]);
        hs[i] = hv;
        h_buf[b * 512 + i] = hv;
        c_buf[b * 512 + i] = bf2f(c0[b * 512 + i]);
    }
    __syncthreads();
    float acc = 0.f;
    const u16* wp = att_w1 + 512 * 256 + t;
    for (int k = 0; k < 512; ++k) acc += hs[k] * bf2f(wp[(size_t)k * 256]);
    hterm[b * 256 + t] = acc;
}

// ---------------- generic tiled GEMM: C = act(A @ Bw + bias) ----------------
// A: [M,K] internal bf16, Bw: [K,N] bf16 row-major, M % 128 == 0
// OMODE 1: store internal bf16; OMODE 2: adaptive final store (flag: bf16/fp32)
template <bool TANH, int OMODE>
__global__ __launch_bounds__(256) void gemm_kernel(const u16* __restrict__ A, int lda,
                                                   const u16* __restrict__ Bw, int ldb,
                                                   const u16* __restrict__ bias,
                                                   void* __restrict__ Cv, int ldc,
                                                   int M, int N, int K,
                                                   const int* __restrict__ flg) {
    __shared__ float As[16][132];
    __shared__ float Bs[16][68];
    int t = threadIdx.x;
    int n0 = blockIdx.x * 64;
    int m0 = blockIdx.y * 128;
    int tx = t & 15, ty = t >> 4;
    float acc[8][4];
#pragma unroll
    for (int i = 0; i < 8; ++i)
#pragma unroll
        for (int j = 0; j < 4; ++j) acc[i][j] = 0.f;

    int ar = t >> 1, akb = (t & 1) * 8;
    int bn = t & 63, bkg = t >> 6;

    for (int k0 = 0; k0 < K; k0 += 16) {
        const u16* Ap = A + (size_t)(m0 + ar) * lda + k0 + akb;
        if (k0 + 16 <= K) {
#pragma unroll
            for (int i = 0; i < 8; ++i) As[akb + i][ar] = bf2f(Ap[i]);
        } else {
#pragma unroll
            for (int i = 0; i < 8; ++i) As[akb + i][ar] = (k0 + akb + i < K) ? bf2f(Ap[i]) : 0.f;
        }
#pragma unroll
        for (int i = 0; i < 4; ++i) {
            int kk = bkg * 4 + i;
            int kg = k0 + kk, ng = n0 + bn;
            Bs[kk][bn] = (kg < K && ng < N) ? bf2f(Bw[(size_t)kg * ldb + ng]) : 0.f;
        }
        __syncthreads();
#pragma unroll
        for (int kk = 0; kk < 16; ++kk) {
            float4 aA = *(const float4*)&As[kk][ty * 8];
            float4 aB = *(const float4*)&As[kk][ty * 8 + 4];
            float4 bv = *(const float4*)&Bs[kk][tx * 4];
            float av[8] = {aA.x, aA.y, aA.z, aA.w, aB.x, aB.y, aB.z, aB.w};
            float bb[4] = {bv.x, bv.y, bv.z, bv.w};
#pragma unroll
            for (int i = 0; i < 8; ++i)
#pragma unroll
                for (int j = 0; j < 4; ++j) acc[i][j] += av[i] * bb[j];
        }
        __syncthreads();
    }
    int obf = (OMODE == 2) ? flg[0] : 1;
    float bb[4];
#pragma unroll
    for (int j = 0; j < 4; ++j) {
        int n = n0 + tx * 4 + j;
        bb[j] = (n < N) ? bf2f(bias[n]) : 0.f;
    }
#pragma unroll
    for (int i = 0; i < 8; ++i) {
        int m = m0 + ty * 8 + i;
#pragma unroll
        for (int j = 0; j < 4; ++j) {
            int n = n0 + tx * 4 + j;
            if (n < N) {
                float v = acc[i][j] + bb[j];
                if (TANH) v = tanhf(v);
                if (OMODE == 1 || obf)
                    ((u16*)Cv)[(size_t)m * ldc + n] = f2bf(v);
                else
                    ((float*)Cv)[(size_t)m * ldc + n] = v;
            }
        }
    }
}

// ---------------- per-step attention MLP (layers 1-3) ----------------
__global__ __launch_bounds__(256) void att_kernel(const u16* __restrict__ att_w2,
                                                  const u16* __restrict__ att_b2,
                                                  const u16* __restrict__ att_w3,
                                                  const u16* __restrict__ pre1,
                                                  const float* __restrict__ hterm,
                                                  float* __restrict__ s_buf) {
    int b = blockIdx.x / 7, ch = blockIdx.x % 7;
    int row0 = b * L_ + ch * 28;
    int t = threadIdx.x;
    __shared__ float x1s[28][260];
    __shared__ float ht[256];
    __shared__ float w3s[128];
    __shared__ float part[28][36];
    ht[t] = hterm[b * 256 + t];
    if (t < 128) w3s[t] = bf2f(att_w3[t]);
    __syncthreads();
#pragma unroll 2
    for (int r = 0; r < 28; ++r)
        x1s[r][t] = tanhf(bf2f(pre1[(size_t)(row0 + r) * 256 + t]) + ht[t]);
    __syncthreads();
    if (t < 224) {
        int r0 = (t >> 5) * 4, c0 = (t & 31) * 4;
        float acc[4][4];
#pragma unroll
        for (int i = 0; i < 4; ++i)
#pragma unroll
            for (int j = 0; j < 4; ++j) acc[i][j] = 0.f;
        for (int k = 0; k < 256; k += 2) {
            float a[4][2];
#pragma unroll
            for (int i = 0; i < 4; ++i) {
                float2 v = *(const float2*)&x1s[r0 + i][k];
                a[i][0] = v.x;
                a[i][1] = v.y;
            }
#pragma unroll
            for (int u = 0; u < 2; ++u) {
                const u16* wp = att_w2 + (size_t)(k + u) * 128 + c0;
#pragma unroll
                for (int j = 0; j < 4; ++j) {
                    float w = bf2f(wp[j]);
#pragma unroll
                    for (int i = 0; i < 4; ++i) acc[i][j] += a[i][u] * w;
                }
            }
        }
#pragma unroll
        for (int i = 0; i < 4; ++i) {
            float p = 0.f;
#pragma unroll
            for (int j = 0; j < 4; ++j)
                p += tanhf(acc[i][j] + bf2f(att_b2[c0 + j])) * w3s[c0 + j];
            part[r0 + i][t & 31] = p;
        }
    }
    __syncthreads();
    if (t < 28) {
        float s = 0.f;
#pragma unroll
        for (int cg = 0; cg < 32; ++cg) s += part[t][cg];
        s_buf[b * L_ + ch * 28 + t] = s;  // att_b3 omitted: softmax-invariant
    }
}

// ---------------- softmax + context z -> hze z-part ----------------
__global__ __launch_bounds__(256) void softz_kernel(const float* __restrict__ s_buf,
                                                    const u16* __restrict__ a,
                                                    u16* __restrict__ hze, int tstep) {
    int b = blockIdx.x >> 1, half = blockIdx.x & 1;
    int t = threadIdx.x;
    __shared__ float red[256];
    __shared__ float alpha[196];
    float v = (t < L_) ? s_buf[b * L_ + t] : -1e30f;
    red[t] = v;
    __syncthreads();
    for (int off = 128; off > 0; off >>= 1) {
        if (t < off) red[t] = fmaxf(red[t], red[t + off]);
        __syncthreads();
    }
    float mx = red[0];
    __syncthreads();
    float e = (t < L_) ? __expf(v - mx) : 0.f;
    red[t] = e;
    __syncthreads();
    for (int off = 128; off > 0; off >>= 1) {
        if (t < off) red[t] += red[t + off];
        __syncthreads();
    }
    float inv = 1.f / red[0];
    __syncthreads();
    if (t < L_) alpha[t] = e * inv;
    __syncthreads();
    int d = half * 256 + t;
    const u16* ap = a + (size_t)b * L_ * 512 + d;
    float z = 0.f;
    for (int l = 0; l < L_; ++l) z += alpha[l] * bf2f(ap[(size_t)l * 512]);
    hze[(size_t)(b * T_ + tstep) * 1280 + 512 + d] = f2bf(z);
}

// ---------------- LSTM gate GEMM (partial over K halves) ----------------
__global__ __launch_bounds__(256) void gates_kernel(const u16* __restrict__ w_ih,
                                                    const u16* __restrict__ w_hh,
                                                    const u16* __restrict__ hze,
                                                    const float* __restrict__ h_buf,
                                                    float* __restrict__ gp, int tstep, int par) {
    int cb = blockIdx.x >> 1, kc = blockIdx.x & 1;
    int col0 = cb * 16;
    int t = threadIdx.x;
    int col = col0 + (t & 15);
    int b0 = (t >> 4) * 2;
    __shared__ float inp[32][129];
    float acc0 = 0.f, acc1 = 0.f;
    int kend = kc * 640 + 640;
    for (int k0 = kc * 640; k0 < kend; k0 += 128) {
#pragma unroll
        for (int i = 0; i < 16; ++i) {
            int idx = i * 256 + t;
            int bb = idx >> 7, kk = idx & 127;
            int k = k0 + kk;
            float v;
            if (k < 512)
                v = bf2f(hze[(size_t)(bb * T_ + tstep) * 1280 + 512 + k]);
            else if (k < 768)
                v = bf2f(hze[(size_t)(bb * T_ + tstep) * 1280 + 1024 + (k - 512)]);
            else
                v = h_buf[par * B_ * H_ + bb * 512 + (k - 768)];
            inp[bb][kk] = v;
        }
        __syncthreads();
        const u16* wbase = (k0 < 768) ? (w_ih + (size_t)k0 * 2048 + col)
                                      : (w_hh + (size_t)(k0 - 768) * 2048 + col);
        for (int kk = 0; kk < 128; kk += 2) {
            float wa = bf2f(wbase[(size_t)kk * 2048]);
            float wb = bf2f(wbase[(size_t)(kk + 1) * 2048]);
            float2 p = *(const float2*)&inp[b0][kk];
            float2 q = *(const float2*)&inp[b0 + 1][kk];
            acc0 += p.x * wa + p.y * wb;
            acc1 += q.x * wa + q.y * wb;
        }
        __syncthreads();
    }
    gp[(size_t)(kc * 32 + b0) * 2048 + col] = acc0;
    gp[(size_t)(kc * 32 + b0 + 1) * 2048 + col] = acc1;
}

// ---------------- gate nonlinearities, h/c update, next hterm ----------------
__global__ __launch_bounds__(256) void update_kernel(const float* __restrict__ gp,
                                                     const u16* __restrict__ b_ih,
                                                     const u16* __restrict__ b_hh,
                                                     const u16* __restrict__ att_w1,
                                                     float* __restrict__ h_buf,
                                                     float* __restrict__ c_buf,
                                                     u16* __restrict__ hze,
                                                     float* __restrict__ hterm, int tstep, int par) {
    int b = blockIdx.x, t = threadIdx.x;
    __shared__ float hs[512];
#pragma unroll
    for (int u = 0; u < 2; ++u) {
        int d = u * 256 + t;
        float g[4];
#pragma unroll
        for (int q = 0; q < 4; ++q) {
            int col = q * 512 + d;
            g[q] = gp[(size_t)b * 2048 + col] + gp[(size_t)(32 + b) * 2048 + col] +
                   bf2f(b_ih[col]) + bf2f(b_hh[col]);
        }
        float ig = sigm(g[0]), fg = sigm(g[1]), gg = tanhf(g[2]), og = sigm(g[3]);
        float cn = fg * c_buf[b * 512 + d] + ig * gg;
        c_buf[b * 512 + d] = cn;
        float h = og * tanhf(cn);
        hs[d] = h;
        h_buf[(1 - par) * B_ * H_ + b * 512 + d] = h;
        hze[(size_t)(b * T_ + tstep) * 1280 + d] = f2bf(h);
    }
    __syncthreads();
    float acc = 0.f;
    const u16* wp = att_w1 + 512 * 256 + t;
    for (int k = 0; k < 512; ++k) acc += hs[k] * bf2f(wp[(size_t)k * 256]);
    hterm[b * 256 + t] = acc;
}

extern "C" void kernel_launch(void* const* d_in, const int* in_sizes, int n_in,
                              void* d_out, int out_size, void* d_ws, size_t ws_size,
                              hipStream_t stream) {
    (void)in_sizes; (void)n_in; (void)out_size; (void)ws_size;
    const int* y = (const int*)d_in[3];

    char* base = (char*)d_ws;
    size_t off = 0;
    auto alloc = [&](size_t bytes) {
        void* p = base + off;
        off = (off + bytes + 63) & ~(size_t)63;
        return p;
    };
    int* flg   = (int*)alloc(64);
    u16* conv  = (u16*)alloc((size_t)7001464 * 2);
    u16* pre1  = (u16*)alloc((size_t)6272 * 256 * 2);
    u16* hze   = (u16*)alloc((size_t)4096 * 1280 * 2);
    u16* t1    = (u16*)alloc((size_t)4096 * 358 * 2);
    u16* t2    = (u16*)alloc((size_t)4096 * 358 * 2);
    float* hterm = (float*)alloc(32 * 256 * 4);
    float* s_buf = (float*)alloc(32 * 196 * 4);
    float* h_buf = (float*)alloc(2 * 32 * 512 * 4);
    float* c_buf = (float*)alloc(32 * 512 * 4);
    float* gp    = (float*)alloc(2 * 32 * 2048 * 4);

    u16* c_a     = conv + 0;
    u16* c_h0    = conv + 3211264;
    u16* c_c0    = conv + 3227648;
    u16* c_attw1 = conv + 3244032;
    u16* c_attb1 = conv + 3440640;
    u16* c_attw2 = conv + 3440896;
    u16* c_attb2 = conv + 3473664;
    u16* c_attw3 = conv + 3473792;
    u16* c_wih   = conv + 3473920;
    u16* c_whh   = conv + 5046784;
    u16* c_bih   = conv + 6095360;
    u16* c_bhh   = conv + 6097408;
    u16* c_emb   = conv + 6099456;
    u16* c_ow1   = conv + 6230528;
    u16* c_ob1   = conv + 6688768;
    u16* c_ow2   = conv + 6689128;
    u16* c_ob2   = conv + 6817296;
    u16* c_ow3   = conv + 6817656;
    u16* c_ob3   = conv + 7000952;

    ConvPtrs cp;
    {
        const int idx[19] = {0, 1, 2, 4, 5, 6, 7, 8, 10, 11, 12, 13, 14, 15, 16, 17, 18, 19, 20};
        for (int i = 0; i < 19; ++i) cp.p[i] = d_in[idx[i]];
    }

    detect_kernel<<<1, 64, 0, stream>>>((const u16*)d_in[4], flg);
    conv_kernel<<<6838, 256, 0, stream>>>(cp, flg, conv);

    embed_kernel<<<1024, 256, 0, stream>>>(y, c_emb, hze);
    init_kernel<<<32, 256, 0, stream>>>(c_h0, c_c0, c_attw1, h_buf, c_buf, hterm);
    gemm_kernel<false, 1><<<dim3(4, 49), 256, 0, stream>>>(
        c_a, 512, c_attw1, 256, c_attb1, pre1, 256, 6272, 256, 512, flg);

    for (int t = 0; t < T_; ++t) {
        int par = t & 1;
        att_kernel<<<224, 256, 0, stream>>>(c_attw2, c_attb2, c_attw3, pre1, hterm, s_buf);
        softz_kernel<<<64, 256, 0, stream>>>(s_buf, c_a, hze, t);
        gates_kernel<<<256, 256, 0, stream>>>(c_wih, c_whh, hze, h_buf, gp, t, par);
        update_kernel<<<32, 256, 0, stream>>>(gp, c_bih, c_bhh, c_attw1, h_buf, c_buf, hze, hterm, t, par);
    }

    gemm_kernel<true, 1><<<dim3(6, 32), 256, 0, stream>>>(
        hze, 1280, c_ow1, 358, c_ob1, t1, 358, 4096, 358, 1280, flg);
    gemm_kernel<true, 1><<<dim3(6, 32), 256, 0, stream>>>(
        t1, 358, c_ow2, 358, c_ob2, t2, 358, 4096, 358, 358, flg);
    gemm_kernel<false, 2><<<dim3(8, 32), 256, 0, stream>>>(
        t2, 358, c_ow3, 512, c_ob3, d_out, 512, 4096, 512, 358, flg);
}